// Round 12
// baseline (106.398 us; speedup 1.0000x reference)
//
#include <hip/hip_runtime.h>
#include <hip/hip_bf16.h>

#define NQ 12
typedef __hip_bfloat16 bf16;

__device__ __forceinline__ float b2f(unsigned int u) {
  union { unsigned int i; float f; } v; v.i = u << 16; return v.f;
}

// Dtype-adaptive scalar load (world: f32 — probe-verified on HW R5/R6/R7/R11).
__device__ __forceinline__ float ldv(const void* p, int i, bool f32) {
  if (f32) return ((const float*)p)[i];
  return b2f((unsigned int)((const unsigned short*)p)[i]);
}

// Composite permutation of the 12 sequential ring CNOTs. HW-verified (R2/R7/R11).
__device__ __forceinline__ int ringperm(int d) {
  int a = d ^ ((d & 1) << 11);
  return a ^ (a >> 1);
}

// LDS bank swizzle. HW-verified conflict-free in R7/R11 (SQ_LDS_BANK_CONFLICT=0).
__device__ __forceinline__ int swz(int p) { return p ^ ((p >> 6) & 31); }

// R7-proven initial product state, layout A: amp[j] = state[(j<<6)|lane].
__device__ __forceinline__ void init_state(const void* x, int bb, bool f32,
                                           int lane, float (&amp)[64]) {
  float lp = 1.f;
#pragma unroll
  for (int q = 6; q < 12; ++q) {
    float h = 0.5f * ldv(x, bb * NQ + q, f32);
    lp *= ((lane >> (11 - q)) & 1) ? __sinf(h) : __cosf(h);
  }
  float h0 = 0.5f * ldv(x, bb * NQ + 0, f32);
  amp[0] = lp * __cosf(h0);
  amp[1] = lp * __sinf(h0);
#pragma unroll
  for (int lvl = 1; lvl < 6; ++lvl) {
    float h = 0.5f * ldv(x, bb * NQ + lvl, f32);
    float cc = __cosf(h), ss = __sinf(h);
#pragma unroll
    for (int i = (1 << lvl) - 1; i >= 0; --i) {
      float t = amp[i];
      amp[2 * i]     = t * cc;
      amp[2 * i + 1] = t * ss;
    }
  }
}

// One wave; TWO batch elements (2*blk, 2*blk+1); 128 amps/lane total.
// Per element the pipeline is the R7/R11-proven one (same addresses, same
// math). The two elements share the 16KB LDS buffer sequentially; source
// order places element-B LDS reads before element-A gates so the compiler
// overlaps DS latency with VALU work (in-wave ILP).
__global__ __launch_bounds__(64) void qsim_kernel(
    const void* __restrict__ x,    // [B,12] f32
    const void* __restrict__ w,    // [2,12] f32
    const void* __restrict__ Wm,   // [2,12] f32
    const void* __restrict__ bv,   // [2]    f32
    void* __restrict__ out)        // [B,2]  f32
{
  __shared__ float st[4096];
  const int lane = threadIdx.x;
  const int bA = 2 * blockIdx.x;
  const int bB = bA + 1;

  // ---- inline dtype probe (HW-proven R5/R6/R7/R11) ----
  bool f32;
  {
    const unsigned short* xu = (const unsigned short*)x;
    int insane = 0;
#pragma unroll
    for (int i = 0; i < 16; ++i) {
      float v = b2f((unsigned int)xu[2 * i]);
      float a = fabsf(v);
      if (!(a <= 64.f) || (a != 0.f && a < 1e-8f)) ++insane;
    }
    f32 = (insane >= 2);
  }

  float ampA[64], ampB[64];
  init_state(x, bA, f32, lane, ampA);
  init_state(x, bB, f32, lane, ampB);

  const int rb1 = swz(ringperm(lane << 6));      // pass-1 read base
  const int wb2 = (lane << 6) ^ (lane & 31);     // pass-2 write base

#pragma unroll 1
  for (int l = 0; l < 2; ++l) {
    // ---- Pass 1 (ring-CNOT perm + transpose A->B layout), element A then B
    __syncthreads();
#pragma unroll
    for (int j = 0; j < 64; ++j) st[((j << 6) ^ (j & 31)) ^ lane] = ampA[j];
    __syncthreads();
#pragma unroll
    for (int j = 0; j < 64; ++j) ampA[j] = st[rb1 ^ swz(ringperm(j))];
    __syncthreads();
#pragma unroll
    for (int j = 0; j < 64; ++j) st[((j << 6) ^ (j & 31)) ^ lane] = ampB[j];
    __syncthreads();
#pragma unroll
    for (int j = 0; j < 64; ++j) ampB[j] = st[rb1 ^ swz(ringperm(j))];

    // ---- RY q6..11: gates on A overlap with B's reads in flight ----
    float cch[6], ssh[6];
#pragma unroll
    for (int q = 6; q < 12; ++q) {
      float h = 0.5f * ldv(w, l * NQ + q, f32);
      cch[q - 6] = __cosf(h); ssh[q - 6] = __sinf(h);
    }
#pragma unroll
    for (int q = 6; q < 12; ++q) {
      const float c = cch[q - 6], s = ssh[q - 6];
      const int m = 1 << (11 - q);
#pragma unroll
      for (int j = 0; j < 64; ++j) {
        if (j & m) continue;
        float v0 = ampA[j], v1 = ampA[j | m];
        ampA[j]     = fmaf(c, v0, -s * v1);
        ampA[j | m] = fmaf(s, v0,  c * v1);
      }
    }
#pragma unroll
    for (int q = 6; q < 12; ++q) {
      const float c = cch[q - 6], s = ssh[q - 6];
      const int m = 1 << (11 - q);
#pragma unroll
      for (int j = 0; j < 64; ++j) {
        if (j & m) continue;
        float v0 = ampB[j], v1 = ampB[j | m];
        ampB[j]     = fmaf(c, v0, -s * v1);
        ampB[j | m] = fmaf(s, v0,  c * v1);
      }
    }

    // ---- Pass 2 (pure transpose back), element A then B ----
    __syncthreads();
#pragma unroll
    for (int j = 0; j < 64; ++j) st[wb2 ^ j] = ampA[j];
    __syncthreads();
#pragma unroll
    for (int j = 0; j < 64; ++j) ampA[j] = st[((j << 6) ^ (j & 31)) ^ lane];
    __syncthreads();
#pragma unroll
    for (int j = 0; j < 64; ++j) st[wb2 ^ j] = ampB[j];
    __syncthreads();
#pragma unroll
    for (int j = 0; j < 64; ++j) ampB[j] = st[((j << 6) ^ (j & 31)) ^ lane];

    // ---- RY q0..5: gates on A overlap with B's reads in flight ----
#pragma unroll
    for (int q = 0; q < 6; ++q) {
      float h = 0.5f * ldv(w, l * NQ + q, f32);
      cch[q] = __cosf(h); ssh[q] = __sinf(h);
    }
#pragma unroll
    for (int q = 0; q < 6; ++q) {
      const float c = cch[q], s = ssh[q];
      const int m = 1 << (5 - q);
#pragma unroll
      for (int j = 0; j < 64; ++j) {
        if (j & m) continue;
        float v0 = ampA[j], v1 = ampA[j | m];
        ampA[j]     = fmaf(c, v0, -s * v1);
        ampA[j | m] = fmaf(s, v0,  c * v1);
      }
    }
#pragma unroll
    for (int q = 0; q < 6; ++q) {
      const float c = cch[q], s = ssh[q];
      const int m = 1 << (5 - q);
#pragma unroll
      for (int j = 0; j < 64; ++j) {
        if (j & m) continue;
        float v0 = ampB[j], v1 = ampB[j | m];
        ampB[j]     = fmaf(c, v0, -s * v1);
        ampB[j | m] = fmaf(s, v0,  c * v1);
      }
    }
  }

  // ---- measurement (R7-verbatim math), both elements ----
  float PA = 0.f, zA0 = 0.f, zA1 = 0.f, zA2 = 0.f, zA3 = 0.f, zA4 = 0.f, zA5 = 0.f;
  float PB = 0.f, zB0 = 0.f, zB1 = 0.f, zB2 = 0.f, zB3 = 0.f, zB4 = 0.f, zB5 = 0.f;
#pragma unroll
  for (int j = 0; j < 64; ++j) {
    float pa = ampA[j] * ampA[j];
    float pb = ampB[j] * ampB[j];
    PA += pa;                      PB += pb;
    zA0 += (j & 32) ? -pa : pa;    zB0 += (j & 32) ? -pb : pb;
    zA1 += (j & 16) ? -pa : pa;    zB1 += (j & 16) ? -pb : pb;
    zA2 += (j & 8)  ? -pa : pa;    zB2 += (j & 8)  ? -pb : pb;
    zA3 += (j & 4)  ? -pa : pa;    zB3 += (j & 4)  ? -pb : pb;
    zA4 += (j & 2)  ? -pa : pa;    zB4 += (j & 2)  ? -pb : pb;
    zA5 += (j & 1)  ? -pa : pa;    zB5 += (j & 1)  ? -pb : pb;
  }

  // ---- fused linear head: shared Wm loads, 4 butterflies ----
  float tA0, tA1, tB0, tB1;
#pragma unroll
  for (int r = 0; r < 2; ++r) {
    float w0 = ldv(Wm, r * NQ + 0, f32), w1 = ldv(Wm, r * NQ + 1, f32),
          w2 = ldv(Wm, r * NQ + 2, f32), w3 = ldv(Wm, r * NQ + 3, f32),
          w4 = ldv(Wm, r * NQ + 4, f32), w5 = ldv(Wm, r * NQ + 5, f32);
    float accA = zA0 * w0 + zA1 * w1 + zA2 * w2 + zA3 * w3 + zA4 * w4 + zA5 * w5;
    float accB = zB0 * w0 + zB1 * w1 + zB2 * w2 + zB3 * w3 + zB4 * w4 + zB5 * w5;
    float wsum = 0.f;
#pragma unroll
    for (int q = 6; q < 12; ++q) {
      float wv = ldv(Wm, r * NQ + q, f32);
      wsum += ((lane >> (11 - q)) & 1) ? -wv : wv;
    }
    accA = fmaf(PA, wsum, accA);
    accB = fmaf(PB, wsum, accB);
    if (r == 0) { tA0 = accA; tB0 = accB; }
    else        { tA1 = accA; tB1 = accB; }
  }
#pragma unroll
  for (int off = 32; off; off >>= 1) {
    tA0 += __shfl_xor(tA0, off, 64);
    tA1 += __shfl_xor(tA1, off, 64);
    tB0 += __shfl_xor(tB0, off, 64);
    tB1 += __shfl_xor(tB1, off, 64);
  }
  if (lane < 2) {
    float o = ((lane == 0) ? tA0 : tA1) + ldv(bv, lane, f32);
    if (f32) ((float*)out)[bA * 2 + lane] = o;
    else     ((bf16*)out)[bA * 2 + lane] = __float2bfloat16(o);
  } else if (lane < 4) {
    int r = lane - 2;
    float o = ((r == 0) ? tB0 : tB1) + ldv(bv, r, f32);
    if (f32) ((float*)out)[bB * 2 + r] = o;
    else     ((bf16*)out)[bB * 2 + r] = __float2bfloat16(o);
  }
}

extern "C" void kernel_launch(void* const* d_in, const int* in_sizes, int n_in,
                              void* d_out, int out_size, void* d_ws, size_t ws_size,
                              hipStream_t stream) {
  const void* x  = d_in[0];
  const void* w  = d_in[1];
  const void* Wm = d_in[2];
  const void* bv = d_in[3];
  const int batch = out_size / 2;   // out is [B, 2]
  qsim_kernel<<<dim3(batch / 2), dim3(64), 0, stream>>>(x, w, Wm, bv, d_out);
}

// Round 13
// 95.087 us; speedup vs baseline: 1.1189x; 1.1189x over previous
//
#include <hip/hip_runtime.h>
#include <hip/hip_bf16.h>

#define NQ 12
typedef __hip_bfloat16 bf16;

__device__ __forceinline__ float b2f(unsigned int u) {
  union { unsigned int i; float f; } v; v.i = u << 16; return v.f;
}

// Dtype-adaptive scalar load (world: f32 — probe-verified on HW R5/R6/R7/R11).
__device__ __forceinline__ float ldv(const void* p, int i, bool f32) {
  if (f32) return ((const float*)p)[i];
  return b2f((unsigned int)((const unsigned short*)p)[i]);
}

// Composite permutation of the 12 sequential ring CNOTs. HW-verified (R2/R7/R11).
__device__ __forceinline__ int ringperm(int d) {
  int a = d ^ ((d & 1) << 11);
  return a ^ (a >> 1);
}

// LDS bank swizzle. HW-verified conflict-free in R7/R11 (SQ_LDS_BANK_CONFLICT=0).
__device__ __forceinline__ int swz(int p) { return p ^ ((p >> 6) & 31); }

// One wave per batch element; 64 amps/lane; 16KB LDS.
// Layout A: amp[j] = state[(j<<6)|lane]; Layout B: amp[j] = state[(lane<<6)|j]
//   (in B, amp[j] holds state[ringperm-image] right after a perm-folding pass).
//
// NEW vs R7/R11: layer 1 starts DIRECTLY in layout B. Input to layer 1 is a
// product state and ringperm is GF(2)-linear, so
//   amp_B[j] = prod_q f_q( bit_{11-q}(rb) ^ e_q(j) ),  rb = ringperm(lane<<6),
// with compile-time e_q(j) from rp(j) bits: b11=b10=j0; b9..b6=0; b5=j5;
// b4=j4^j5; b3=j3^j4; b2=j2^j3; b1=j1^j2; b0=j0^j1. This removes the whole
// first LDS pass (128 DS ops) and 2 of 8 barriers at equal VALU cost.
// All remaining passes/gates/measurement are the R7/R11-proven lines verbatim.
__global__ __launch_bounds__(64) void qsim_kernel(
    const void* __restrict__ x,    // [B,12] f32
    const void* __restrict__ w,    // [2,12] f32
    const void* __restrict__ Wm,   // [2,12] f32
    const void* __restrict__ bv,   // [2]    f32
    void* __restrict__ out)        // [B,2]  f32
{
  __shared__ float st[4096];
  const int lane = threadIdx.x;
  const int b = blockIdx.x;

  // ---- inline dtype probe (HW-proven R5/R6/R7/R11) ----
  bool f32;
  {
    const unsigned short* xu = (const unsigned short*)x;
    int insane = 0;
#pragma unroll
    for (int i = 0; i < 16; ++i) {
      float v = b2f((unsigned int)xu[2 * i]);
      float a = fabsf(v);
      if (!(a <= 64.f) || (a != 0.f && a < 1e-8f)) ++insane;
    }
    f32 = (insane >= 2);
  }

  // ---- direct init in layout B (layer-1 CNOT perm folded, no LDS) ----
  float amp[64];
  {
    float csx[12], snx[12];
#pragma unroll
    for (int q = 0; q < 12; ++q) {
      float h = 0.5f * ldv(x, b * NQ + q, f32);
      csx[q] = __cosf(h); snx[q] = __sinf(h);
    }
    const int rb = ringperm(lane << 6);   // runtime per-lane, proven map
    float f0[12], f1[12];                 // f_q at e=0 / e=1
#pragma unroll
    for (int q = 0; q < 12; ++q) {
      int r = (rb >> (11 - q)) & 1;
      f0[q] = r ? snx[q] : csx[q];
      f1[q] = r ? csx[q] : snx[q];
    }
    const float K   = f0[2] * f0[3] * f0[4] * f0[5];  // qubits 2..5: e=0
    const float h0f = f0[0] * f0[1];                  // qubits 0,1: e=j0
    const float h1f = f1[0] * f1[1];
    // u(j1,j0) = t11(j0^j1) * h(j0)
    const float u00 = f0[11] * h0f, u01 = f1[11] * h1f;
    const float u10 = f1[11] * h0f, u11 = f0[11] * h1f;
#pragma unroll
    for (int j5 = 0; j5 < 2; ++j5) {
      const float a5 = K * (j5 ? f1[6] : f0[6]);
#pragma unroll
      for (int j4 = 0; j4 < 2; ++j4) {
        const float a4 = a5 * ((j4 ^ j5) ? f1[7] : f0[7]);
#pragma unroll
        for (int j3 = 0; j3 < 2; ++j3) {
          const float a3 = a4 * ((j3 ^ j4) ? f1[8] : f0[8]);
#pragma unroll
          for (int j2 = 0; j2 < 2; ++j2) {
            const float a2 = a3 * ((j2 ^ j3) ? f1[9] : f0[9]);
#pragma unroll
            for (int j1 = 0; j1 < 2; ++j1) {
              const float a1 = a2 * ((j1 ^ j2) ? f1[10] : f0[10]);
#pragma unroll
              for (int j0 = 0; j0 < 2; ++j0) {
                const float uu = j1 ? (j0 ? u11 : u10) : (j0 ? u01 : u00);
                amp[(j5 << 5) | (j4 << 4) | (j3 << 3) | (j2 << 2) | (j1 << 1) | j0]
                    = a1 * uu;
              }
            }
          }
        }
      }
    }
  }

  const int rb1 = swz(ringperm(lane << 6));      // pass-1 read base (l=1)
  const int wb2 = (lane << 6) ^ (lane & 31);     // pass-2 write base

#pragma unroll 1
  for (int l = 0; l < 2; ++l) {
    if (l) {
      // ---- Pass 1: ring-CNOT perm + transpose A -> B (layer 2 only) ----
      __syncthreads();
#pragma unroll
      for (int j = 0; j < 64; ++j) st[((j << 6) ^ (j & 31)) ^ lane] = amp[j];
      __syncthreads();
#pragma unroll
      for (int j = 0; j < 64; ++j) amp[j] = st[rb1 ^ swz(ringperm(j))];
    }

    // ---- RY gates, qubits 6..11 (register pairs in layout B) ----
#pragma unroll
    for (int q = 6; q < 12; ++q) {
      float h = 0.5f * ldv(w, l * NQ + q, f32);
      const float c = __cosf(h), s = __sinf(h);
      const int m = 1 << (11 - q);
#pragma unroll
      for (int j = 0; j < 64; ++j) {
        if (j & m) continue;
        float v0 = amp[j], v1 = amp[j | m];
        amp[j]     = fmaf(c, v0, -s * v1);
        amp[j | m] = fmaf(s, v0,  c * v1);
      }
    }

    // ---- Pass 2: pure transpose, B -> A ----
    __syncthreads();
#pragma unroll
    for (int j = 0; j < 64; ++j) st[wb2 ^ j] = amp[j];
    __syncthreads();
#pragma unroll
    for (int j = 0; j < 64; ++j) amp[j] = st[((j << 6) ^ (j & 31)) ^ lane];

    // ---- RY gates, qubits 0..5 (register pairs in layout A) ----
#pragma unroll
    for (int q = 0; q < 6; ++q) {
      float h = 0.5f * ldv(w, l * NQ + q, f32);
      const float c = __cosf(h), s = __sinf(h);
      const int m = 1 << (5 - q);
#pragma unroll
      for (int j = 0; j < 64; ++j) {
        if (j & m) continue;
        float v0 = amp[j], v1 = amp[j | m];
        amp[j]     = fmaf(c, v0, -s * v1);
        amp[j | m] = fmaf(s, v0,  c * v1);
      }
    }
  }

  // ---- measurement in layout A (R7-verbatim) ----
  float P = 0.f, z0 = 0.f, z1 = 0.f, z2 = 0.f, z3 = 0.f, z4 = 0.f, z5 = 0.f;
#pragma unroll
  for (int j = 0; j < 64; ++j) {
    float pr = amp[j] * amp[j];
    P  += pr;
    z0 += (j & 32) ? -pr : pr;
    z1 += (j & 16) ? -pr : pr;
    z2 += (j & 8)  ? -pr : pr;
    z3 += (j & 4)  ? -pr : pr;
    z4 += (j & 2)  ? -pr : pr;
    z5 += (j & 1)  ? -pr : pr;
  }

  // ---- fused linear head (R7-verbatim) ----
  float t0, t1;
#pragma unroll
  for (int r = 0; r < 2; ++r) {
    float acc = z0 * ldv(Wm, r * NQ + 0, f32) + z1 * ldv(Wm, r * NQ + 1, f32)
              + z2 * ldv(Wm, r * NQ + 2, f32) + z3 * ldv(Wm, r * NQ + 3, f32)
              + z4 * ldv(Wm, r * NQ + 4, f32) + z5 * ldv(Wm, r * NQ + 5, f32);
    float wsum = 0.f;
#pragma unroll
    for (int q = 6; q < 12; ++q) {
      float wv = ldv(Wm, r * NQ + q, f32);
      wsum += ((lane >> (11 - q)) & 1) ? -wv : wv;
    }
    acc = fmaf(P, wsum, acc);
    if (r == 0) t0 = acc; else t1 = acc;
  }
#pragma unroll
  for (int off = 32; off; off >>= 1) {
    t0 += __shfl_xor(t0, off, 64);
    t1 += __shfl_xor(t1, off, 64);
  }
  if (lane < 2) {
    float o = ((lane == 0) ? t0 : t1) + ldv(bv, lane, f32);
    if (f32) ((float*)out)[b * 2 + lane] = o;
    else     ((bf16*)out)[b * 2 + lane] = __float2bfloat16(o);
  }
}

extern "C" void kernel_launch(void* const* d_in, const int* in_sizes, int n_in,
                              void* d_out, int out_size, void* d_ws, size_t ws_size,
                              hipStream_t stream) {
  const void* x  = d_in[0];
  const void* w  = d_in[1];
  const void* Wm = d_in[2];
  const void* bv = d_in[3];
  const int batch = out_size / 2;   // out is [B, 2]
  qsim_kernel<<<dim3(batch), dim3(64), 0, stream>>>(x, w, Wm, bv, d_out);
}

// Round 14
// 87.437 us; speedup vs baseline: 1.2169x; 1.0875x over previous
//
#include <hip/hip_runtime.h>
#include <hip/hip_bf16.h>

#define NQ 12
typedef __hip_bfloat16 bf16;
typedef float v2f __attribute__((ext_vector_type(2)));

__device__ __forceinline__ float b2f(unsigned int u) {
  union { unsigned int i; float f; } v; v.i = u << 16; return v.f;
}

// Dtype-adaptive scalar load (world: f32 — probe-verified on HW R5/R6/R7/R11).
__device__ __forceinline__ float ldv(const void* p, int i, bool f32) {
  if (f32) return ((const float*)p)[i];
  return b2f((unsigned int)((const unsigned short*)p)[i]);
}

// Composite permutation of the 12 sequential ring CNOTs. HW-verified (R2/R7/R11/R13).
__device__ __forceinline__ int ringperm(int d) {
  int a = d ^ ((d & 1) << 11);
  return a ^ (a >> 1);
}

// LDS bank swizzle. HW-verified conflict-free (SQ_LDS_BANK_CONFLICT=0, R7..R13).
__device__ __forceinline__ int swz(int p) { return p ^ ((p >> 6) & 31); }

// One wave per batch element; state in 32 packed float2 regs (64 amps/lane).
// amp[k] holds (j=2k, j=2k+1) of the current layout — R13 structure verbatim,
// arithmetic regrouped into <2 x float> so the backend emits v_pk_{mul,fma}_f32
// (22 of 24 gates have pair-mask >= 2 -> packable; q5/q11 scalar in-element).
// LDS pass addresses are byte-identical to R13 (no new address algebra).
__global__ __launch_bounds__(64) void qsim_kernel(
    const void* __restrict__ x,    // [B,12] f32
    const void* __restrict__ w,    // [2,12] f32
    const void* __restrict__ Wm,   // [2,12] f32
    const void* __restrict__ bv,   // [2]    f32
    void* __restrict__ out)        // [B,2]  f32
{
  __shared__ float st[4096];
  const int lane = threadIdx.x;
  const int b = blockIdx.x;

  // ---- inline dtype probe (HW-proven R5/R6/R7/R11/R13) ----
  bool f32;
  {
    const unsigned short* xu = (const unsigned short*)x;
    int insane = 0;
#pragma unroll
    for (int i = 0; i < 16; ++i) {
      float v = b2f((unsigned int)xu[2 * i]);
      float a = fabsf(v);
      if (!(a <= 64.f) || (a != 0.f && a < 1e-8f)) ++insane;
    }
    f32 = (insane >= 2);
  }

  // ---- direct init in layout B (layer-1 CNOT perm folded, no LDS; R13) ----
  v2f amp[32];
  {
    float csx[12], snx[12];
#pragma unroll
    for (int q = 0; q < 12; ++q) {
      float h = 0.5f * ldv(x, b * NQ + q, f32);
      csx[q] = __cosf(h); snx[q] = __sinf(h);
    }
    const int rb = ringperm(lane << 6);
    float f0[12], f1[12];
#pragma unroll
    for (int q = 0; q < 12; ++q) {
      int r = (rb >> (11 - q)) & 1;
      f0[q] = r ? snx[q] : csx[q];
      f1[q] = r ? csx[q] : snx[q];
    }
    const float K   = f0[2] * f0[3] * f0[4] * f0[5];
    const float h0f = f0[0] * f0[1];
    const float h1f = f1[0] * f1[1];
    const float u00 = f0[11] * h0f, u01 = f1[11] * h1f;
    const float u10 = f1[11] * h0f, u11 = f0[11] * h1f;
#pragma unroll
    for (int j5 = 0; j5 < 2; ++j5) {
      const float a5 = K * (j5 ? f1[6] : f0[6]);
#pragma unroll
      for (int j4 = 0; j4 < 2; ++j4) {
        const float a4 = a5 * ((j4 ^ j5) ? f1[7] : f0[7]);
#pragma unroll
        for (int j3 = 0; j3 < 2; ++j3) {
          const float a3 = a4 * ((j3 ^ j4) ? f1[8] : f0[8]);
#pragma unroll
          for (int j2 = 0; j2 < 2; ++j2) {
            const float a2 = a3 * ((j2 ^ j3) ? f1[9] : f0[9]);
#pragma unroll
            for (int j1 = 0; j1 < 2; ++j1) {
              const float a1 = a2 * ((j1 ^ j2) ? f1[10] : f0[10]);
              const int k = (j5 << 4) | (j4 << 3) | (j3 << 2) | (j2 << 1) | j1;
              amp[k].x = a1 * (j1 ? u10 : u00);
              amp[k].y = a1 * (j1 ? u11 : u01);
            }
          }
        }
      }
    }
  }

  const int rb1 = swz(ringperm(lane << 6));      // pass-1 read base (l=1)
  const int wb2 = (lane << 6) ^ (lane & 31);     // pass-2 write base

#pragma unroll 1
  for (int l = 0; l < 2; ++l) {
    if (l) {
      // ---- Pass 1: ring-CNOT perm + transpose A -> B (layer 2; R13 addrs) ----
      __syncthreads();
#pragma unroll
      for (int j = 0; j < 64; ++j)
        st[((j << 6) ^ (j & 31)) ^ lane] = amp[j >> 1][j & 1];
      __syncthreads();
#pragma unroll
      for (int j = 0; j < 64; ++j)
        amp[j >> 1][j & 1] = st[rb1 ^ swz(ringperm(j))];
    }

    // ---- RY gates, qubits 6..10 (packed pairs, layout B) ----
#pragma unroll
    for (int q = 6; q < 11; ++q) {
      float h = 0.5f * ldv(w, l * NQ + q, f32);
      const float c = __cosf(h), s = __sinf(h);
      const int hm = 1 << (10 - q);        // pair mask in k-space (m>>1)
#pragma unroll
      for (int k = 0; k < 32; ++k) {
        if (k & hm) continue;
        v2f v0 = amp[k], v1 = amp[k | hm];
        amp[k]      = c * v0 - s * v1;
        amp[k | hm] = s * v0 + c * v1;
      }
    }
    // ---- RY q11 (m=1: scalar within each packed element) ----
    {
      float h = 0.5f * ldv(w, l * NQ + 11, f32);
      const float c = __cosf(h), s = __sinf(h);
#pragma unroll
      for (int k = 0; k < 32; ++k) {
        float xx = amp[k].x, yy = amp[k].y;
        amp[k].x = fmaf(c, xx, -s * yy);
        amp[k].y = fmaf(s, xx,  c * yy);
      }
    }

    // ---- Pass 2: pure transpose, B -> A (R13 addrs) ----
    __syncthreads();
#pragma unroll
    for (int j = 0; j < 64; ++j)
      st[wb2 ^ j] = amp[j >> 1][j & 1];
    __syncthreads();
#pragma unroll
    for (int j = 0; j < 64; ++j)
      amp[j >> 1][j & 1] = st[((j << 6) ^ (j & 31)) ^ lane];

    // ---- RY gates, qubits 0..4 (packed pairs, layout A) ----
#pragma unroll
    for (int q = 0; q < 5; ++q) {
      float h = 0.5f * ldv(w, l * NQ + q, f32);
      const float c = __cosf(h), s = __sinf(h);
      const int hm = 1 << (4 - q);
#pragma unroll
      for (int k = 0; k < 32; ++k) {
        if (k & hm) continue;
        v2f v0 = amp[k], v1 = amp[k | hm];
        amp[k]      = c * v0 - s * v1;
        amp[k | hm] = s * v0 + c * v1;
      }
    }
    // ---- RY q5 (m=1: scalar within each packed element) ----
    {
      float h = 0.5f * ldv(w, l * NQ + 5, f32);
      const float c = __cosf(h), s = __sinf(h);
#pragma unroll
      for (int k = 0; k < 32; ++k) {
        float xx = amp[k].x, yy = amp[k].y;
        amp[k].x = fmaf(c, xx, -s * yy);
        amp[k].y = fmaf(s, xx,  c * yy);
      }
    }
  }

  // ---- measurement in layout A (packed; j=2k+h -> j bits map to k bits) ----
  v2f Pv = {0.f, 0.f}, zv0 = Pv, zv1 = Pv, zv2 = Pv, zv3 = Pv, zv4 = Pv;
  float z5 = 0.f;
#pragma unroll
  for (int k = 0; k < 32; ++k) {
    v2f pr = amp[k] * amp[k];
    Pv += pr;
    zv0 += (k & 16) ? -pr : pr;   // j&32
    zv1 += (k & 8)  ? -pr : pr;   // j&16
    zv2 += (k & 4)  ? -pr : pr;   // j&8
    zv3 += (k & 2)  ? -pr : pr;   // j&4
    zv4 += (k & 1)  ? -pr : pr;   // j&2
    z5  += pr.x - pr.y;           // j&1
  }
  const float P  = Pv.x + Pv.y;
  const float z0 = zv0.x + zv0.y, z1 = zv1.x + zv1.y, z2 = zv2.x + zv2.y;
  const float z3 = zv3.x + zv3.y, z4 = zv4.x + zv4.y;

  // ---- fused linear head (R13-verbatim) ----
  float t0, t1;
#pragma unroll
  for (int r = 0; r < 2; ++r) {
    float acc = z0 * ldv(Wm, r * NQ + 0, f32) + z1 * ldv(Wm, r * NQ + 1, f32)
              + z2 * ldv(Wm, r * NQ + 2, f32) + z3 * ldv(Wm, r * NQ + 3, f32)
              + z4 * ldv(Wm, r * NQ + 4, f32) + z5 * ldv(Wm, r * NQ + 5, f32);
    float wsum = 0.f;
#pragma unroll
    for (int q = 6; q < 12; ++q) {
      float wv = ldv(Wm, r * NQ + q, f32);
      wsum += ((lane >> (11 - q)) & 1) ? -wv : wv;
    }
    acc = fmaf(P, wsum, acc);
    if (r == 0) t0 = acc; else t1 = acc;
  }
#pragma unroll
  for (int off = 32; off; off >>= 1) {
    t0 += __shfl_xor(t0, off, 64);
    t1 += __shfl_xor(t1, off, 64);
  }
  if (lane < 2) {
    float o = ((lane == 0) ? t0 : t1) + ldv(bv, lane, f32);
    if (f32) ((float*)out)[b * 2 + lane] = o;
    else     ((bf16*)out)[b * 2 + lane] = __float2bfloat16(o);
  }
}

extern "C" void kernel_launch(void* const* d_in, const int* in_sizes, int n_in,
                              void* d_out, int out_size, void* d_ws, size_t ws_size,
                              hipStream_t stream) {
  const void* x  = d_in[0];
  const void* w  = d_in[1];
  const void* Wm = d_in[2];
  const void* bv = d_in[3];
  const int batch = out_size / 2;   // out is [B, 2]
  qsim_kernel<<<dim3(batch), dim3(64), 0, stream>>>(x, w, Wm, bv, d_out);
}

// Round 15
// 85.936 us; speedup vs baseline: 1.2381x; 1.0175x over previous
//
#include <hip/hip_runtime.h>
#include <hip/hip_bf16.h>

#define NQ 12
typedef __hip_bfloat16 bf16;
typedef float v2f __attribute__((ext_vector_type(2)));

__device__ __forceinline__ float b2f(unsigned int u) {
  union { unsigned int i; float f; } v; v.i = u << 16; return v.f;
}

// Dtype-adaptive scalar load (world: f32 — probe-verified on HW R5..R14).
__device__ __forceinline__ float ldv(const void* p, int i, bool f32) {
  if (f32) return ((const float*)p)[i];
  return b2f((unsigned int)((const unsigned short*)p)[i]);
}

// Composite permutation of the 12 sequential ring CNOTs. HW-verified (R2..R14).
__device__ __forceinline__ int ringperm(int d) {
  int a = d ^ ((d & 1) << 11);
  return a ^ (a >> 1);
}

// LDS bank swizzle. HW-verified conflict-free (SQ_LDS_BANK_CONFLICT=0, R7..R14).
__device__ __forceinline__ int swz(int p) { return p ^ ((p >> 6) & 31); }

// One wave per batch element; state in 32 packed float2 regs (64 amps/lane).
// Structure = R14 (proven, ~34us) with two arithmetic-identity changes:
//  (1) gates use the 3-shear Givens form (3 pk-fma vs 4 pk-ops):
//      v0 -= t*v1; v1 += s*v0; v0 -= t*v1,  t=tan(h/2), s=sin(h).
//  (2) layer-2 RYs are never applied to the state: <Z_q>_final =
//      cos(th_q)<Z_q> - sin(th_q)<X_q> of the post-CNOT state (RY^ Z RY =
//      cos Z - sin X; other-qubit RYs commute). <X_q> = sum_d psi(d)psi(d^m_q)
//      computed with plain single-bit masks: q6..11 register-local in layout B
//      (after the kept perm-folding pass-1), q0..5 register-local in layout A
//      (after the kept pass-2). LDS lines are R13/R14-verbatim.
__global__ __launch_bounds__(64) void qsim_kernel(
    const void* __restrict__ x,    // [B,12] f32
    const void* __restrict__ w,    // [2,12] f32
    const void* __restrict__ Wm,   // [2,12] f32
    const void* __restrict__ bv,   // [2]    f32
    void* __restrict__ out)        // [B,2]  f32
{
  __shared__ float st[4096];
  const int lane = threadIdx.x;
  const int b = blockIdx.x;

  // ---- inline dtype probe (HW-proven R5..R14) ----
  bool f32;
  {
    const unsigned short* xu = (const unsigned short*)x;
    int insane = 0;
#pragma unroll
    for (int i = 0; i < 16; ++i) {
      float v = b2f((unsigned int)xu[2 * i]);
      float a = fabsf(v);
      if (!(a <= 64.f) || (a != 0.f && a < 1e-8f)) ++insane;
    }
    f32 = (insane >= 2);
  }

  // ---- direct init in layout B (layer-1 CNOT perm folded, no LDS; R13/R14) ----
  v2f amp[32];
  {
    float csx[12], snx[12];
#pragma unroll
    for (int q = 0; q < 12; ++q) {
      float h = 0.5f * ldv(x, b * NQ + q, f32);
      csx[q] = __cosf(h); snx[q] = __sinf(h);
    }
    const int rb = ringperm(lane << 6);
    float f0[12], f1[12];
#pragma unroll
    for (int q = 0; q < 12; ++q) {
      int r = (rb >> (11 - q)) & 1;
      f0[q] = r ? snx[q] : csx[q];
      f1[q] = r ? csx[q] : snx[q];
    }
    const float K   = f0[2] * f0[3] * f0[4] * f0[5];
    const float h0f = f0[0] * f0[1];
    const float h1f = f1[0] * f1[1];
    const float u00 = f0[11] * h0f, u01 = f1[11] * h1f;
    const float u10 = f1[11] * h0f, u11 = f0[11] * h1f;
#pragma unroll
    for (int j5 = 0; j5 < 2; ++j5) {
      const float a5 = K * (j5 ? f1[6] : f0[6]);
#pragma unroll
      for (int j4 = 0; j4 < 2; ++j4) {
        const float a4 = a5 * ((j4 ^ j5) ? f1[7] : f0[7]);
#pragma unroll
        for (int j3 = 0; j3 < 2; ++j3) {
          const float a3 = a4 * ((j3 ^ j4) ? f1[8] : f0[8]);
#pragma unroll
          for (int j2 = 0; j2 < 2; ++j2) {
            const float a2 = a3 * ((j2 ^ j3) ? f1[9] : f0[9]);
#pragma unroll
            for (int j1 = 0; j1 < 2; ++j1) {
              const float a1 = a2 * ((j1 ^ j2) ? f1[10] : f0[10]);
              const int k = (j5 << 4) | (j4 << 3) | (j3 << 2) | (j2 << 1) | j1;
              amp[k].x = a1 * (j1 ? u10 : u00);
              amp[k].y = a1 * (j1 ? u11 : u01);
            }
          }
        }
      }
    }
  }

  const int rb1 = swz(ringperm(lane << 6));      // layer-2 pass-1 read base
  const int wb2 = (lane << 6) ^ (lane & 31);     // pass-2 write base

  // ================= layer 1: RY gates (3-shear form) =================
  // ---- q6..10 packed (layout B), q11 in-element ----
#pragma unroll
  for (int q = 6; q < 11; ++q) {
    float h = 0.5f * ldv(w, 0 * NQ + q, f32);
    const float t = __tanf(0.5f * h), s = __sinf(h);
    const int hm = 1 << (10 - q);
#pragma unroll
    for (int k = 0; k < 32; ++k) {
      if (k & hm) continue;
      amp[k]      += -t * amp[k | hm];
      amp[k | hm] +=  s * amp[k];
      amp[k]      += -t * amp[k | hm];
    }
  }
  {
    float h = 0.5f * ldv(w, 0 * NQ + 11, f32);
    const float t = __tanf(0.5f * h), s = __sinf(h);
#pragma unroll
    for (int k = 0; k < 32; ++k) {
      amp[k].x = fmaf(-t, amp[k].y, amp[k].x);
      amp[k].y = fmaf( s, amp[k].x, amp[k].y);
      amp[k].x = fmaf(-t, amp[k].y, amp[k].x);
    }
  }

  // ---- pass 2: pure transpose B -> A (R14-verbatim) ----
  __syncthreads();
#pragma unroll
  for (int j = 0; j < 64; ++j)
    st[wb2 ^ j] = amp[j >> 1][j & 1];
  __syncthreads();
#pragma unroll
  for (int j = 0; j < 64; ++j)
    amp[j >> 1][j & 1] = st[((j << 6) ^ (j & 31)) ^ lane];

  // ---- q0..4 packed (layout A), q5 in-element ----
#pragma unroll
  for (int q = 0; q < 5; ++q) {
    float h = 0.5f * ldv(w, 0 * NQ + q, f32);
    const float t = __tanf(0.5f * h), s = __sinf(h);
    const int hm = 1 << (4 - q);
#pragma unroll
    for (int k = 0; k < 32; ++k) {
      if (k & hm) continue;
      amp[k]      += -t * amp[k | hm];
      amp[k | hm] +=  s * amp[k];
      amp[k]      += -t * amp[k | hm];
    }
  }
  {
    float h = 0.5f * ldv(w, 0 * NQ + 5, f32);
    const float t = __tanf(0.5f * h), s = __sinf(h);
#pragma unroll
    for (int k = 0; k < 32; ++k) {
      amp[k].x = fmaf(-t, amp[k].y, amp[k].x);
      amp[k].y = fmaf( s, amp[k].x, amp[k].y);
      amp[k].x = fmaf(-t, amp[k].y, amp[k].x);
    }
  }

  // ================= layer 2: CNOT perm only; RYs folded =================
  // ---- pass 1: ring-CNOT perm + transpose A -> B (R14-verbatim) ----
  __syncthreads();
#pragma unroll
  for (int j = 0; j < 64; ++j)
    st[((j << 6) ^ (j & 31)) ^ lane] = amp[j >> 1][j & 1];
  __syncthreads();
#pragma unroll
  for (int j = 0; j < 64; ++j)
    amp[j >> 1][j & 1] = st[rb1 ^ swz(ringperm(j))];

  // ---- <X_q> partials, q6..11 (register-local in layout B) ----
  float xB6, xB7, xB8, xB9, xB10, xB11;
  {
    v2f a6 = {0.f, 0.f}, a7 = a6, a8 = a6, a9 = a6, a10 = a6;
    float a11 = 0.f;
#pragma unroll
    for (int k = 0; k < 32; ++k) {
      a6  += amp[k] * amp[k ^ 16];
      a7  += amp[k] * amp[k ^ 8];
      a8  += amp[k] * amp[k ^ 4];
      a9  += amp[k] * amp[k ^ 2];
      a10 += amp[k] * amp[k ^ 1];
      a11 += amp[k].x * amp[k].y;
    }
    xB6 = a6.x + a6.y; xB7 = a7.x + a7.y; xB8 = a8.x + a8.y;
    xB9 = a9.x + a9.y; xB10 = a10.x + a10.y; xB11 = 2.f * a11;
  }

  // ---- pass 2: pure transpose B -> A (R14-verbatim) ----
  __syncthreads();
#pragma unroll
  for (int j = 0; j < 64; ++j)
    st[wb2 ^ j] = amp[j >> 1][j & 1];
  __syncthreads();
#pragma unroll
  for (int j = 0; j < 64; ++j)
    amp[j >> 1][j & 1] = st[((j << 6) ^ (j & 31)) ^ lane];

  // ---- <X_q> partials, q0..5 (register-local in layout A) ----
  float xA0, xA1, xA2, xA3, xA4, xA5;
  {
    v2f a0 = {0.f, 0.f}, a1 = a0, a2 = a0, a3 = a0, a4 = a0;
    float a5 = 0.f;
#pragma unroll
    for (int k = 0; k < 32; ++k) {
      a0 += amp[k] * amp[k ^ 16];
      a1 += amp[k] * amp[k ^ 8];
      a2 += amp[k] * amp[k ^ 4];
      a3 += amp[k] * amp[k ^ 2];
      a4 += amp[k] * amp[k ^ 1];
      a5 += amp[k].x * amp[k].y;
    }
    xA0 = a0.x + a0.y; xA1 = a1.x + a1.y; xA2 = a2.x + a2.y;
    xA3 = a3.x + a3.y; xA4 = a4.x + a4.y; xA5 = 2.f * a5;
  }

  // ---- <Z_q> partials (R14-verbatim measurement, layout A) ----
  v2f Pv = {0.f, 0.f}, zv0 = Pv, zv1 = Pv, zv2 = Pv, zv3 = Pv, zv4 = Pv;
  float z5 = 0.f;
#pragma unroll
  for (int k = 0; k < 32; ++k) {
    v2f pr = amp[k] * amp[k];
    Pv += pr;
    zv0 += (k & 16) ? -pr : pr;
    zv1 += (k & 8)  ? -pr : pr;
    zv2 += (k & 4)  ? -pr : pr;
    zv3 += (k & 2)  ? -pr : pr;
    zv4 += (k & 1)  ? -pr : pr;
    z5  += pr.x - pr.y;
  }
  const float P  = Pv.x + Pv.y;
  const float z0 = zv0.x + zv0.y, z1 = zv1.x + zv1.y, z2 = zv2.x + zv2.y;
  const float z3 = zv3.x + zv3.y, z4 = zv4.x + zv4.y;

  // ---- layer-2 angles (FULL angle): <Z>_final = ct*Z - st*X ----
  float ct[12], sn[12];
#pragma unroll
  for (int q = 0; q < 12; ++q) {
    float th = ldv(w, NQ + q, f32);
    ct[q] = __cosf(th); sn[q] = __sinf(th);
  }
  const float zA[6] = {z0, z1, z2, z3, z4, z5};
  const float xA[6] = {xA0, xA1, xA2, xA3, xA4, xA5};
  const float xB[6] = {xB6, xB7, xB8, xB9, xB10, xB11};

  // ---- fused linear head ----
  float t0, t1;
#pragma unroll
  for (int r = 0; r < 2; ++r) {
    float acc = 0.f, wsum = 0.f;
#pragma unroll
    for (int q = 0; q < 6; ++q) {
      float wv = ldv(Wm, r * NQ + q, f32);
      acc = fmaf(wv, fmaf(ct[q], zA[q], -sn[q] * xA[q]), acc);
    }
#pragma unroll
    for (int q = 6; q < 12; ++q) {
      float wv = ldv(Wm, r * NQ + q, f32);
      float wc = wv * ct[q];
      wsum += ((lane >> (11 - q)) & 1) ? -wc : wc;
      acc = fmaf(-wv * sn[q], xB[q - 6], acc);
    }
    acc = fmaf(P, wsum, acc);
    if (r == 0) t0 = acc; else t1 = acc;
  }
#pragma unroll
  for (int off = 32; off; off >>= 1) {
    t0 += __shfl_xor(t0, off, 64);
    t1 += __shfl_xor(t1, off, 64);
  }
  if (lane < 2) {
    float o = ((lane == 0) ? t0 : t1) + ldv(bv, lane, f32);
    if (f32) ((float*)out)[b * 2 + lane] = o;
    else     ((bf16*)out)[b * 2 + lane] = __float2bfloat16(o);
  }
}

extern "C" void kernel_launch(void* const* d_in, const int* in_sizes, int n_in,
                              void* d_out, int out_size, void* d_ws, size_t ws_size,
                              hipStream_t stream) {
  const void* x  = d_in[0];
  const void* w  = d_in[1];
  const void* Wm = d_in[2];
  const void* bv = d_in[3];
  const int batch = out_size / 2;   // out is [B, 2]
  qsim_kernel<<<dim3(batch), dim3(64), 0, stream>>>(x, w, Wm, bv, d_out);
}

// Round 16
// 84.426 us; speedup vs baseline: 1.2602x; 1.0179x over previous
//
#include <hip/hip_runtime.h>
#include <hip/hip_bf16.h>

#define NQ 12
typedef __hip_bfloat16 bf16;
typedef float v2f __attribute__((ext_vector_type(2)));

__device__ __forceinline__ float b2f(unsigned int u) {
  union { unsigned int i; float f; } v; v.i = u << 16; return v.f;
}

// Dtype-adaptive scalar load (world: f32 — probe-verified on HW R5..R15).
__device__ __forceinline__ float ldv(const void* p, int i, bool f32) {
  if (f32) return ((const float*)p)[i];
  return b2f((unsigned int)((const unsigned short*)p)[i]);
}

// Composite permutation of the 12 sequential ring CNOTs. HW-verified (R2..R15).
__device__ __forceinline__ int ringperm(int d) {
  int a = d ^ ((d & 1) << 11);
  return a ^ (a >> 1);
}

// LDS bank swizzle. HW-verified conflict-free (SQ_LDS_BANK_CONFLICT=0, R7..R15).
__device__ __forceinline__ int swz(int p) { return p ^ ((p >> 6) & 31); }

// One wave per batch element; state in 32 packed float2 regs (64 amps/lane).
// Structure = R15 (proven: total 85.9us, absmax 1.2e-4) with ONE change:
// the <X_q> pair-correlation loops iterate unordered pairs once and scale by
// 2 (sum_k amp[k]*amp[k^m] = 2*sum_{k&m=0}), halving the packed X products.
__global__ __launch_bounds__(64) void qsim_kernel(
    const void* __restrict__ x,    // [B,12] f32
    const void* __restrict__ w,    // [2,12] f32
    const void* __restrict__ Wm,   // [2,12] f32
    const void* __restrict__ bv,   // [2]    f32
    void* __restrict__ out)        // [B,2]  f32
{
  __shared__ float st[4096];
  const int lane = threadIdx.x;
  const int b = blockIdx.x;

  // ---- inline dtype probe (HW-proven R5..R15) ----
  bool f32;
  {
    const unsigned short* xu = (const unsigned short*)x;
    int insane = 0;
#pragma unroll
    for (int i = 0; i < 16; ++i) {
      float v = b2f((unsigned int)xu[2 * i]);
      float a = fabsf(v);
      if (!(a <= 64.f) || (a != 0.f && a < 1e-8f)) ++insane;
    }
    f32 = (insane >= 2);
  }

  // ---- direct init in layout B (layer-1 CNOT perm folded, no LDS; R13..R15) ----
  v2f amp[32];
  {
    float csx[12], snx[12];
#pragma unroll
    for (int q = 0; q < 12; ++q) {
      float h = 0.5f * ldv(x, b * NQ + q, f32);
      csx[q] = __cosf(h); snx[q] = __sinf(h);
    }
    const int rb = ringperm(lane << 6);
    float f0[12], f1[12];
#pragma unroll
    for (int q = 0; q < 12; ++q) {
      int r = (rb >> (11 - q)) & 1;
      f0[q] = r ? snx[q] : csx[q];
      f1[q] = r ? csx[q] : snx[q];
    }
    const float K   = f0[2] * f0[3] * f0[4] * f0[5];
    const float h0f = f0[0] * f0[1];
    const float h1f = f1[0] * f1[1];
    const float u00 = f0[11] * h0f, u01 = f1[11] * h1f;
    const float u10 = f1[11] * h0f, u11 = f0[11] * h1f;
#pragma unroll
    for (int j5 = 0; j5 < 2; ++j5) {
      const float a5 = K * (j5 ? f1[6] : f0[6]);
#pragma unroll
      for (int j4 = 0; j4 < 2; ++j4) {
        const float a4 = a5 * ((j4 ^ j5) ? f1[7] : f0[7]);
#pragma unroll
        for (int j3 = 0; j3 < 2; ++j3) {
          const float a3 = a4 * ((j3 ^ j4) ? f1[8] : f0[8]);
#pragma unroll
          for (int j2 = 0; j2 < 2; ++j2) {
            const float a2 = a3 * ((j2 ^ j3) ? f1[9] : f0[9]);
#pragma unroll
            for (int j1 = 0; j1 < 2; ++j1) {
              const float a1 = a2 * ((j1 ^ j2) ? f1[10] : f0[10]);
              const int k = (j5 << 4) | (j4 << 3) | (j3 << 2) | (j2 << 1) | j1;
              amp[k].x = a1 * (j1 ? u10 : u00);
              amp[k].y = a1 * (j1 ? u11 : u01);
            }
          }
        }
      }
    }
  }

  const int rb1 = swz(ringperm(lane << 6));      // layer-2 pass-1 read base
  const int wb2 = (lane << 6) ^ (lane & 31);     // pass-2 write base

  // ================= layer 1: RY gates (3-shear form; R15) =================
#pragma unroll
  for (int q = 6; q < 11; ++q) {
    float h = 0.5f * ldv(w, 0 * NQ + q, f32);
    const float t = __tanf(0.5f * h), s = __sinf(h);
    const int hm = 1 << (10 - q);
#pragma unroll
    for (int k = 0; k < 32; ++k) {
      if (k & hm) continue;
      amp[k]      += -t * amp[k | hm];
      amp[k | hm] +=  s * amp[k];
      amp[k]      += -t * amp[k | hm];
    }
  }
  {
    float h = 0.5f * ldv(w, 0 * NQ + 11, f32);
    const float t = __tanf(0.5f * h), s = __sinf(h);
#pragma unroll
    for (int k = 0; k < 32; ++k) {
      amp[k].x = fmaf(-t, amp[k].y, amp[k].x);
      amp[k].y = fmaf( s, amp[k].x, amp[k].y);
      amp[k].x = fmaf(-t, amp[k].y, amp[k].x);
    }
  }

  // ---- pass 2: pure transpose B -> A (R14/R15-verbatim) ----
  __syncthreads();
#pragma unroll
  for (int j = 0; j < 64; ++j)
    st[wb2 ^ j] = amp[j >> 1][j & 1];
  __syncthreads();
#pragma unroll
  for (int j = 0; j < 64; ++j)
    amp[j >> 1][j & 1] = st[((j << 6) ^ (j & 31)) ^ lane];

  // ---- q0..4 packed (layout A), q5 in-element (R15) ----
#pragma unroll
  for (int q = 0; q < 5; ++q) {
    float h = 0.5f * ldv(w, 0 * NQ + q, f32);
    const float t = __tanf(0.5f * h), s = __sinf(h);
    const int hm = 1 << (4 - q);
#pragma unroll
    for (int k = 0; k < 32; ++k) {
      if (k & hm) continue;
      amp[k]      += -t * amp[k | hm];
      amp[k | hm] +=  s * amp[k];
      amp[k]      += -t * amp[k | hm];
    }
  }
  {
    float h = 0.5f * ldv(w, 0 * NQ + 5, f32);
    const float t = __tanf(0.5f * h), s = __sinf(h);
#pragma unroll
    for (int k = 0; k < 32; ++k) {
      amp[k].x = fmaf(-t, amp[k].y, amp[k].x);
      amp[k].y = fmaf( s, amp[k].x, amp[k].y);
      amp[k].x = fmaf(-t, amp[k].y, amp[k].x);
    }
  }

  // ================= layer 2: CNOT perm only; RYs folded (R15) =============
  // ---- pass 1: ring-CNOT perm + transpose A -> B (verbatim) ----
  __syncthreads();
#pragma unroll
  for (int j = 0; j < 64; ++j)
    st[((j << 6) ^ (j & 31)) ^ lane] = amp[j >> 1][j & 1];
  __syncthreads();
#pragma unroll
  for (int j = 0; j < 64; ++j)
    amp[j >> 1][j & 1] = st[rb1 ^ swz(ringperm(j))];

  // ---- <X_q> partials, q6..11 (register-local in B; halved pairs) ----
  float xB6, xB7, xB8, xB9, xB10, xB11;
  {
    v2f a6 = {0.f, 0.f}, a7 = a6, a8 = a6, a9 = a6, a10 = a6;
    float a11 = 0.f;
#pragma unroll
    for (int k = 0; k < 32; ++k) {
      if (!(k & 16)) a6  += amp[k] * amp[k | 16];
      if (!(k & 8))  a7  += amp[k] * amp[k | 8];
      if (!(k & 4))  a8  += amp[k] * amp[k | 4];
      if (!(k & 2))  a9  += amp[k] * amp[k | 2];
      if (!(k & 1))  a10 += amp[k] * amp[k | 1];
      a11 += amp[k].x * amp[k].y;
    }
    xB6 = 2.f * (a6.x + a6.y);  xB7 = 2.f * (a7.x + a7.y);
    xB8 = 2.f * (a8.x + a8.y);  xB9 = 2.f * (a9.x + a9.y);
    xB10 = 2.f * (a10.x + a10.y); xB11 = 2.f * a11;
  }

  // ---- pass 2: pure transpose B -> A (verbatim) ----
  __syncthreads();
#pragma unroll
  for (int j = 0; j < 64; ++j)
    st[wb2 ^ j] = amp[j >> 1][j & 1];
  __syncthreads();
#pragma unroll
  for (int j = 0; j < 64; ++j)
    amp[j >> 1][j & 1] = st[((j << 6) ^ (j & 31)) ^ lane];

  // ---- <X_q> partials, q0..5 (register-local in A; halved pairs) ----
  float xA0, xA1, xA2, xA3, xA4, xA5;
  {
    v2f a0 = {0.f, 0.f}, a1 = a0, a2 = a0, a3 = a0, a4 = a0;
    float a5 = 0.f;
#pragma unroll
    for (int k = 0; k < 32; ++k) {
      if (!(k & 16)) a0 += amp[k] * amp[k | 16];
      if (!(k & 8))  a1 += amp[k] * amp[k | 8];
      if (!(k & 4))  a2 += amp[k] * amp[k | 4];
      if (!(k & 2))  a3 += amp[k] * amp[k | 2];
      if (!(k & 1))  a4 += amp[k] * amp[k | 1];
      a5 += amp[k].x * amp[k].y;
    }
    xA0 = 2.f * (a0.x + a0.y);  xA1 = 2.f * (a1.x + a1.y);
    xA2 = 2.f * (a2.x + a2.y);  xA3 = 2.f * (a3.x + a3.y);
    xA4 = 2.f * (a4.x + a4.y);  xA5 = 2.f * a5;
  }

  // ---- <Z_q> partials (R14/R15-verbatim, layout A) ----
  v2f Pv = {0.f, 0.f}, zv0 = Pv, zv1 = Pv, zv2 = Pv, zv3 = Pv, zv4 = Pv;
  float z5 = 0.f;
#pragma unroll
  for (int k = 0; k < 32; ++k) {
    v2f pr = amp[k] * amp[k];
    Pv += pr;
    zv0 += (k & 16) ? -pr : pr;
    zv1 += (k & 8)  ? -pr : pr;
    zv2 += (k & 4)  ? -pr : pr;
    zv3 += (k & 2)  ? -pr : pr;
    zv4 += (k & 1)  ? -pr : pr;
    z5  += pr.x - pr.y;
  }
  const float P  = Pv.x + Pv.y;
  const float z0 = zv0.x + zv0.y, z1 = zv1.x + zv1.y, z2 = zv2.x + zv2.y;
  const float z3 = zv3.x + zv3.y, z4 = zv4.x + zv4.y;

  // ---- layer-2 angles (FULL angle): <Z>_final = ct*Z - st*X (R15) ----
  float ct[12], sn[12];
#pragma unroll
  for (int q = 0; q < 12; ++q) {
    float th = ldv(w, NQ + q, f32);
    ct[q] = __cosf(th); sn[q] = __sinf(th);
  }
  const float zA[6] = {z0, z1, z2, z3, z4, z5};
  const float xA[6] = {xA0, xA1, xA2, xA3, xA4, xA5};
  const float xB[6] = {xB6, xB7, xB8, xB9, xB10, xB11};

  // ---- fused linear head (R15-verbatim) ----
  float t0, t1;
#pragma unroll
  for (int r = 0; r < 2; ++r) {
    float acc = 0.f, wsum = 0.f;
#pragma unroll
    for (int q = 0; q < 6; ++q) {
      float wv = ldv(Wm, r * NQ + q, f32);
      acc = fmaf(wv, fmaf(ct[q], zA[q], -sn[q] * xA[q]), acc);
    }
#pragma unroll
    for (int q = 6; q < 12; ++q) {
      float wv = ldv(Wm, r * NQ + q, f32);
      float wc = wv * ct[q];
      wsum += ((lane >> (11 - q)) & 1) ? -wc : wc;
      acc = fmaf(-wv * sn[q], xB[q - 6], acc);
    }
    acc = fmaf(P, wsum, acc);
    if (r == 0) t0 = acc; else t1 = acc;
  }
#pragma unroll
  for (int off = 32; off; off >>= 1) {
    t0 += __shfl_xor(t0, off, 64);
    t1 += __shfl_xor(t1, off, 64);
  }
  if (lane < 2) {
    float o = ((lane == 0) ? t0 : t1) + ldv(bv, lane, f32);
    if (f32) ((float*)out)[b * 2 + lane] = o;
    else     ((bf16*)out)[b * 2 + lane] = __float2bfloat16(o);
  }
}

extern "C" void kernel_launch(void* const* d_in, const int* in_sizes, int n_in,
                              void* d_out, int out_size, void* d_ws, size_t ws_size,
                              hipStream_t stream) {
  const void* x  = d_in[0];
  const void* w  = d_in[1];
  const void* Wm = d_in[2];
  const void* bv = d_in[3];
  const int batch = out_size / 2;   // out is [B, 2]
  qsim_kernel<<<dim3(batch), dim3(64), 0, stream>>>(x, w, Wm, bv, d_out);
}